// Round 21
// baseline (202.595 us; speedup 1.0000x reference)
//
#include <hip/hip_runtime.h>
#include <math.h>

#define NN 50000
#define EE 800000
#define FIN 128
#define HID 64
#define CL 40
#define SCB 256
#define NBLK ((NN + SCB - 1) / SCB)  // 196
#define NHB 64       // histogram blocks
#define EPB 12500    // EE / NHB
#define QW 256  // QKVS row width in ushorts (512B, line-aligned segments)

typedef unsigned char uchar_t;
typedef unsigned short ushort_t;
typedef unsigned int uint_t;
typedef float f32x2 __attribute__((ext_vector_type(2)));
typedef float f32x4 __attribute__((ext_vector_type(4)));
typedef short s16x8 __attribute__((ext_vector_type(8)));

#if defined(__has_builtin)
#if __has_builtin(__builtin_amdgcn_cvt_pk_f32_fp8)
#define HAVE_CVT_FP8 1
#endif
#endif

__device__ __forceinline__ ushort_t f2bf(float f) {
  uint_t u = __float_as_uint(f);
  u = (u + 0x7FFFu + ((u >> 16) & 1u)) >> 16;  // RNE
  return (ushort_t)u;
}
__device__ __forceinline__ uint_t f2bf2(float lo, float hi) {
  return (uint_t)f2bf(lo) | ((uint_t)f2bf(hi) << 16);
}
__device__ __forceinline__ float bflo(uint_t u) {
  return __uint_as_float(u << 16);
}
__device__ __forceinline__ float bfhi(uint_t u) {
  return __uint_as_float(u & 0xFFFF0000u);
}

// e4m3fn (OCP) manual encode, RNE; |x|<2^-6 flushed to 0; clamp 448.
__device__ __forceinline__ uint_t f32_to_fp8(float f) {
  uint_t u = __float_as_uint(f);
  uint_t s = (u >> 31) << 7;
  uint_t mag = u & 0x7FFFFFFFu;
  if (mag < 0x3C800000u) return s;            // < 2^-6 -> 0
  if (mag > 0x43E00000u) mag = 0x43E00000u;   // clamp 448
  uint_t r = mag + 0x7FFFFu + ((mag >> 20) & 1u);
  if (r > 0x43E00000u) r = 0x43E00000u;
  return s | (((r - (120u << 23)) >> 20) & 0x7Fu);
}
__device__ __forceinline__ void fp8x4_to_f32(uint_t u, float* o) {
#ifdef HAVE_CVT_FP8
  f32x2 lo = __builtin_amdgcn_cvt_pk_f32_fp8(u, false);
  f32x2 hi = __builtin_amdgcn_cvt_pk_f32_fp8(u, true);
  o[0] = lo[0]; o[1] = lo[1]; o[2] = hi[0]; o[3] = hi[1];
#else
#pragma unroll
  for (int i = 0; i < 4; ++i) {
    uint_t b = (u >> (8 * i)) & 0xFFu;
    uint_t em = b & 0x7Fu;
    uint_t bits = ((b & 0x80u) << 24) | ((em << 20) + (120u << 23));
    o[i] = em ? __uint_as_float(bits) : 0.f;
  }
#endif
}

__device__ __forceinline__ int wave_sum_i(int v) {
#pragma unroll
  for (int off = 32; off > 0; off >>= 1) v += __shfl_xor(v, off, 64);
  return v;
}
__device__ __forceinline__ float wave_sum_f(float v) {
#pragma unroll
  for (int off = 32; off > 0; off >>= 1) v += __shfl_xor(v, off, 64);
  return v;
}
__device__ __forceinline__ float half_sum(float v) {  // within 32-lane half
#pragma unroll
  for (int off = 16; off > 0; off >>= 1) v += __shfl_xor(v, off, 64);
  return v;
}
__device__ __forceinline__ float half_max(float v) {
#pragma unroll
  for (int off = 16; off > 0; off >>= 1) v = fmaxf(v, __shfl_xor(v, off, 64));
  return v;
}
__device__ __forceinline__ float gelu_exact(float x) {
  return 0.5f * x * (1.0f + erff(x * 0.70710678118654752f));
}
__device__ __forceinline__ float leaky02(float x) {
  return x >= 0.f ? x : 0.2f * x;
}

// ------------- fused prep: prepw | wvec | xcast(+fp8) --------------------------
#define PREP_W 169       // ceil(43168/256)
#define PREP_X 12500     // NN/4 nodes per 256-thread block
__global__ __launch_bounds__(256) void k_prep(
    const float* __restrict__ x,
    const float* __restrict__ W0, const float* __restrict__ W1,
    const float* __restrict__ W2, const float* __restrict__ W3,
    const float* __restrict__ Q0, const float* __restrict__ Q1,
    const float* __restrict__ Q2, const float* __restrict__ Q3,
    const float* __restrict__ b0, const float* __restrict__ b1,
    const float* __restrict__ b2, const float* __restrict__ b3,
    const float* __restrict__ attS, const float* __restrict__ attD,
    ushort_t* __restrict__ WtA, ushort_t* __restrict__ WtB,
    float* __restrict__ bcat, float* __restrict__ wv,
    uint_t* __restrict__ xbu, ushort_t* __restrict__ xb8,
    float* __restrict__ a_s, float* __restrict__ a_d) {
  int b = blockIdx.x, t = threadIdx.x;
  if (b < PREP_W) {
    int idx = b * 256 + t;
    if (idx < 32768) {
      int m = idx >> 13, r = idx & 8191, c = r >> 7, k = r & 127;
      const float* W = (m == 0) ? W0 : (m == 1) ? W1 : (m == 2) ? W2 : W3;
      WtA[idx] = f2bf(W[k * HID + c]);
    } else if (idx < 43008) {
      int j = idx - 32768;
      int c = j >> 6, k = j & 63;
      int mm = c / CL, cc = c % CL;
      const float* W = (mm == 0) ? Q0 : (mm == 1) ? Q1 : (mm == 2) ? Q2 : Q3;
      WtB[j] = f2bf(W[k * CL + cc]);
    } else if (idx < 43168) {
      int c = idx - 43008;
      int mm = c / CL, cc = c % CL;
      const float* bb = (mm == 0) ? b0 : (mm == 1) ? b1 : (mm == 2) ? b2 : b3;
      bcat[c] = bb[cc];
    }
  } else if (b < PREP_W + 1) {
    // wvec: wv[0][k] = sum_c W_gat[k][c]*attS[c]; wv[1][k] = ..attD
    int which = t >> 7, k = t & 127;
    const float* att = which ? attD : attS;
    float s = 0.f;
    for (int c = 0; c < HID; ++c) s = fmaf(W2[k * HID + c], att[c], s);
    wv[which * FIN + k] = s;
  } else {
    int node = (b - PREP_W - 1) * 4 + (t >> 6);
    int l = t & 63;
    if (node < NN) {
      float2 xv = ((const float2*)x)[(size_t)node * 64 + l];  // feats 2l,2l+1
      float2 wsv = ((const float2*)wv)[l];
      float2 wdv = ((const float2*)(wv + FIN))[l];
      float ps = fmaf(xv.x, wsv.x, xv.y * wsv.y);
      float pd = fmaf(xv.x, wdv.x, xv.y * wdv.y);
      ps = wave_sum_f(ps);
      pd = wave_sum_f(pd);
      xbu[(size_t)node * 64 + l] = f2bf2(xv.x, xv.y);
      xb8[(size_t)node * 64 + l] =
          (ushort_t)(f32_to_fp8(xv.x) | (f32_to_fp8(xv.y) << 8));
      if (l == 0) { a_s[node] = ps; a_d[node] = pd; }
    }
  }
}

// ------------- LDS histogram, single pass, 8-bit packed counters ---------------
__global__ __launch_bounds__(1024) void k_hist(const int* __restrict__ dst,
                                               int* __restrict__ erank,
                                               uchar_t* __restrict__ histG) {
  __shared__ uint_t hl[NN / 4];  // 12500 uints = 50000 byte counters
  int b = blockIdx.x, t = threadIdx.x;
  for (int i = t; i < NN / 4; i += 1024) hl[i] = 0;
  __syncthreads();
  int ebase = b * EPB;
  for (int i = t; i < EPB; i += 1024) {
    int e = ebase + i;
    int d = dst[e];
    uint_t sh = (uint_t)(d & 3) * 8u;
    uint_t old = atomicAdd(&hl[d >> 2], 1u << sh);
    erank[e] = (int)((old >> sh) & 0xFFu);
  }
  __syncthreads();
  uint_t* hg = (uint_t*)(histG + (size_t)b * NN);
  for (int i = t; i < NN / 4; i += 1024) hg[i] = hl[i];
}

// ---------------- block sums over the 64 mini-histograms -----------------------
__global__ __launch_bounds__(SCB) void k_bsum(const uchar_t* __restrict__ histG,
                                              int* __restrict__ bsum) {
  __shared__ int wsm[4];
  int i = blockIdx.x * SCB + threadIdx.x;
  int v = 0;
  if (i < NN) {
    for (int r = 0; r < NHB; ++r) v += histG[(size_t)r * NN + i];
  }
  int s = wave_sum_i(v);
  int lane = threadIdx.x & 63, wv = threadIdx.x >> 6;
  if (lane == 0) wsm[wv] = s;
  __syncthreads();
  if (threadIdx.x == 0) bsum[blockIdx.x] = wsm[0] + wsm[1] + wsm[2] + wsm[3];
}

// ---------------- fused bscan+apply + per-histblock bases + aux packs ----------
__global__ __launch_bounds__(SCB) void k_scanapply(
    const uchar_t* __restrict__ histG, const int* __restrict__ bsum,
    const float* __restrict__ a_s, const float* __restrict__ a_d,
    int* __restrict__ cnt, int* __restrict__ offs, int* __restrict__ baseT,
    float* __restrict__ dinv, float2* __restrict__ auxS,
    float2* __restrict__ auxD) {
  __shared__ int ts[SCB];
  __shared__ int wred[4];
  int b = blockIdx.x, t = threadIdx.x;
  int pv = (t < b) ? bsum[t] : 0;  // b<=195, t<b implies t<196=NBLK
  int ps = wave_sum_i(pv);
  int lane = t & 63, wv = t >> 6;
  if (lane == 0) wred[wv] = ps;
  int i = b * SCB + t;
  int v = 0;
  if (i < NN) {
    for (int r = 0; r < NHB; ++r) v += histG[(size_t)r * NN + i];
  }
  ts[t] = v;
  __syncthreads();
  int prefix = wred[0] + wred[1] + wred[2] + wred[3];
  for (int off = 1; off < SCB; off <<= 1) {
    int u = (t >= off) ? ts[t - off] : 0;
    __syncthreads();
    ts[t] += u;
    __syncthreads();
  }
  if (i < NN) {
    int ex = ts[t] - v + prefix;
    offs[i] = ex;
    cnt[i] = v;
    float dv = rsqrtf((float)v + 1.0f);
    dinv[i] = dv;
    auxS[i] = make_float2(dv, a_s[i]);
    auxD[i] = make_float2(dv, a_d[i]);
    int run = ex;
    for (int r = 0; r < NHB; ++r) {
      baseT[(size_t)r * NN + i] = run;
      run += histG[(size_t)r * NN + i];
    }
  }
}

// ---------------- scatter pass 1: inverse permutation only (4B/edge) -----------
__global__ __launch_bounds__(256) void k_sc1(const int* __restrict__ dst,
                                             const int* __restrict__ erank,
                                             const int* __restrict__ baseT,
                                             int* __restrict__ esorted) {
  int e = blockIdx.x * blockDim.x + threadIdx.x;
  if (e < EE) {
    int d = dst[e];
    int blk = e / EPB;  // must match k_hist's block->edge mapping
    esorted[baseT[(size_t)blk * NN + d] + erank[e]] = e;
  }
}

// ---------------- scatter pass 2: p-coalesced fill of sorted arrays ------------
__global__ __launch_bounds__(256) void k_sc2(
    const int* __restrict__ esorted, const int* __restrict__ src,
    const int* __restrict__ dst, const float2* __restrict__ auxS,
    const float2* __restrict__ auxD, int* __restrict__ srcidx,
    int* __restrict__ dsts, float2* __restrict__ edata) {
  int p = blockIdx.x * blockDim.x + threadIdx.x;
  if (p < EE) {
    int e = esorted[p];
    int s = src[e], d = dst[e];
    srcidx[p] = s;
    dsts[p] = d;
    float2 A = auxS[s];  // {dinv_s, a_s_s}
    float2 B = auxD[d];  // {dinv_d, a_d_d}
    float ex = __expf(leaky02(A.y + B.y));
    edata[p] = make_float2(A.x * B.x, ex);
  }
}

// ---------------- x-space aggregation (fp8 gathers, 8 edges/half in flight) ----
__global__ __launch_bounds__(256) void k_agg1x(
    const int* __restrict__ srcidx, const int* __restrict__ offs,
    const int* __restrict__ cnt, const uint_t* __restrict__ xb8u,
    const uint_t* __restrict__ xbu, const float2* __restrict__ edata,
    const float* __restrict__ dinv, const float* __restrict__ a_s,
    const float* __restrict__ a_d, uint_t* __restrict__ aggu) {
  int node = (blockIdx.x * blockDim.x + threadIdx.x) >> 6;
  int lane = threadIdx.x & 63;
  if (node >= NN) return;
  const int half = lane >> 5;
  const int fl = lane & 31;
  int beg = offs[node];
  int c = cnt[node];
  int end = beg + c;
  float g[4] = {0.f, 0.f, 0.f, 0.f};
  float sS[4] = {0.f, 0.f, 0.f, 0.f};
  float tA[4] = {0.f, 0.f, 0.f, 0.f};
  float dg = 0.f;
  int p = beg + half;
  // 8 edges per half-wave in flight (16/wave): hide gather latency.
  for (; p + 14 < end; p += 16) {
    int sI[8];
    float2 eI[8];
    uint_t uI[8];
#pragma unroll
    for (int k = 0; k < 8; ++k) {
      sI[k] = srcidx[p + 2 * k];
      eI[k] = edata[p + 2 * k];
    }
#pragma unroll
    for (int k = 0; k < 8; ++k) uI[k] = xb8u[(size_t)sI[k] * 32 + fl];
#pragma unroll
    for (int k = 0; k < 8; ++k) {
      float A[4];
      fp8x4_to_f32(uI[k], A);
#pragma unroll
      for (int i = 0; i < 4; ++i) {
        g[i] = fmaf(A[i], eI[k].x, g[i]);
        sS[i] += A[i];
        tA[i] = fmaf(A[i], eI[k].y, tA[i]);
      }
      dg += eI[k].y;
    }
  }
  for (; p < end; p += 2) {
    int s0 = srcidx[p];
    float2 e0 = edata[p];
    uint_t u0 = xb8u[(size_t)s0 * 32 + fl];
    float A[4];
    fp8x4_to_f32(u0, A);
#pragma unroll
    for (int i = 0; i < 4; ++i) {
      g[i] = fmaf(A[i], e0.x, g[i]);
      sS[i] += A[i];
      tA[i] = fmaf(A[i], e0.y, tA[i]);
    }
    dg += e0.y;
  }
  // fold halves
#pragma unroll
  for (int i = 0; i < 4; ++i) {
    g[i] += __shfl_xor(g[i], 32, 64);
    sS[i] += __shfl_xor(sS[i], 32, 64);
    tA[i] += __shfl_xor(tA[i], 32, 64);
  }
  dg += __shfl_xor(dg, 32, 64);
  // self-loops (bf16 x) + scaling
  float dd = dinv[node];
  float exl = __expf(leaky02(a_s[node] + a_d[node]));
  uint_t n0 = xbu[(size_t)node * 64 + 2 * fl];
  uint_t n1 = xbu[(size_t)node * 64 + 2 * fl + 1];
  float X[4] = {bflo(n0), bfhi(n0), bflo(n1), bfhi(n1)};
  float dd2 = dd * dd;
  float cinv = 1.0f / fmaxf((float)c, 1.0f);
  float gdi = 1.0f / (dg + exl + 1e-16f);
#pragma unroll
  for (int i = 0; i < 4; ++i) {
    g[i] = fmaf(X[i], dd2, g[i]);
    tA[i] = fmaf(X[i], exl, tA[i]);
    sS[i] *= cinv;
    tA[i] *= gdi;
  }
  if (half == 0) {
    uint_t* ag = aggu + (size_t)node * 192;
    ag[2 * fl] = f2bf2(g[0], g[1]);
    ag[2 * fl + 1] = f2bf2(g[2], g[3]);
    ag[64 + 2 * fl] = f2bf2(sS[0], sS[1]);
    ag[64 + 2 * fl + 1] = f2bf2(sS[2], sS[3]);
    ag[128 + 2 * fl] = f2bf2(tA[0], tA[1]);
    ag[128 + 2 * fl + 1] = f2bf2(tA[2], tA[3]);
  }
}

// ---------------- post GEMM: 4 MFMA matmuls + gelu ensemble --------------------
__global__ __launch_bounds__(256) void k_post(
    const ushort_t* __restrict__ agg, const ushort_t* __restrict__ xb,
    const ushort_t* __restrict__ WtA, const float* __restrict__ b_gcn,
    const float* __restrict__ bl, const float* __restrict__ b_gat,
    const float* __restrict__ w, ushort_t* __restrict__ ensb) {
  __shared__ __align__(16) ushort_t wlds[64 * 136];  // [c][k] pad +8
  const int t = threadIdx.x;
  const int wv = t >> 6, l = t & 63;
  const int lr = l & 15, lg = l >> 4;
  const int rbase = blockIdx.x * 64 + wv * 16;
  int arow = rbase + lr;
  int arowc = arow < NN ? arow : NN - 1;
  f32x4 acc[4][4] = {};
#pragma unroll
  for (int m = 0; m < 4; ++m) {
    if (m) __syncthreads();
    for (int idx = t; idx < 64 * 16; idx += 256) {
      int c = idx >> 4, ch = idx & 15;
      *(uint4*)&wlds[c * 136 + ch * 8] =
          *(const uint4*)(WtA + m * 8192 + c * 128 + ch * 8);
    }
    __syncthreads();
    const ushort_t* ap = (m < 3) ? agg + (size_t)arowc * 384 + m * 128 + lg * 8
                                 : xb + (size_t)arowc * 128 + lg * 8;
#pragma unroll
    for (int ks = 0; ks < 4; ++ks) {
      s16x8 af = *(const s16x8*)(ap + ks * 32);
#pragma unroll
      for (int n = 0; n < 4; ++n) {
        s16x8 bf = *(const s16x8*)&wlds[(n * 16 + lr) * 136 + ks * 32 + lg * 8];
        acc[m][n] =
            __builtin_amdgcn_mfma_f32_16x16x32_bf16(af, bf, acc[m][n], 0, 0, 0);
      }
    }
  }
  float w0 = w[0], w1 = w[1], w2 = w[2];
#pragma unroll
  for (int n = 0; n < 4; ++n) {
    int col = n * 16 + lr;
    float bgv = b_gcn[col], bsv = bl[col], bav = b_gat[col];
#pragma unroll
    for (int j = 0; j < 4; ++j) {
      int orow = rbase + lg * 4 + j;
      if (orow < NN) {
        float g = gelu_exact(acc[0][n][j] + bgv);
        float s = gelu_exact(acc[1][n][j] + acc[3][n][j] + bsv);
        float tt = gelu_exact(acc[2][n][j] + bav);
        ensb[(size_t)orow * 64 + col] = f2bf(w0 * g + w1 * s + w2 * tt);
      }
    }
  }
}

// ---------------- MFMA GEMM B: line-aligned QKVS (segments at 0/64/128/192) ----
__global__ __launch_bounds__(256) void k_gemmB(
    const ushort_t* __restrict__ ensb, const ushort_t* __restrict__ WtB,
    const float* __restrict__ bcat, ushort_t* __restrict__ QKVSb) {
  __shared__ __align__(16) ushort_t wb[160 * 72];  // [c][k] padded +8
  __shared__ float bsh[160];
  const int t = threadIdx.x;
  for (int idx = t; idx < 160 * 8; idx += 256) {
    int c = idx >> 3, ch = idx & 7;
    *(uint4*)&wb[c * 72 + ch * 8] = *(const uint4*)(WtB + c * 64 + ch * 8);
  }
  if (t < 160) bsh[t] = bcat[t];
  __syncthreads();
  const int wv = t >> 6, l = t & 63;
  const int lr = l & 15, lg = l >> 4;
  const int rbase = blockIdx.x * 64 + wv * 16;
  int arow = rbase + lr;
  int arowc = arow < NN ? arow : NN - 1;
  const ushort_t* ap = ensb + (size_t)arowc * 64 + lg * 8;
  f32x4 acc[10] = {};
#pragma unroll
  for (int ks = 0; ks < 2; ++ks) {
    s16x8 af = *(const s16x8*)(ap + ks * 32);
#pragma unroll
    for (int n = 0; n < 10; ++n) {
      s16x8 bf = *(const s16x8*)&wb[(n * 16 + lr) * 72 + ks * 32 + lg * 8];
      acc[n] = __builtin_amdgcn_mfma_f32_16x16x32_bf16(af, bf, acc[n], 0, 0, 0);
    }
  }
#pragma unroll
  for (int n = 0; n < 10; ++n) {
    int col = n * 16 + lr;
    int seg = col / CL;
    int off = seg * 64 + (col - seg * CL);
#pragma unroll
    for (int j = 0; j < 4; ++j) {
      int orow = rbase + lg * 4 + j;
      if (orow < NN)
        QKVSb[(size_t)orow * QW + off] = f2bf(acc[n][j] + bsh[col]);
    }
  }
}

// ---------------- transformer scores: lane per edge (no shuffles) --------------
__global__ __launch_bounds__(256) void k_score(
    const int* __restrict__ srcidx, const int* __restrict__ dsts,
    const ushort_t* __restrict__ QKVSb, float* __restrict__ escore) {
  int p = blockIdx.x * 256 + threadIdx.x;
  if (p >= EE) return;
  int s = srcidx[p], d = dsts[p];
  const uint4* qp = (const uint4*)(QKVSb + (size_t)d * QW);       // q: line 0
  const uint4* kp = (const uint4*)(QKVSb + (size_t)s * QW + 64);  // k: line 1
  float dot = 0.f;
#pragma unroll
  for (int i = 0; i < 5; ++i) {
    uint4 q = qp[i], k = kp[i];
    dot = fmaf(bflo(q.x), bflo(k.x), dot);
    dot = fmaf(bfhi(q.x), bfhi(k.x), dot);
    dot = fmaf(bflo(q.y), bflo(k.y), dot);
    dot = fmaf(bfhi(q.y), bfhi(k.y), dot);
    dot = fmaf(bflo(q.z), bflo(k.z), dot);
    dot = fmaf(bfhi(q.z), bfhi(k.z), dot);
    dot = fmaf(bflo(q.w), bflo(k.w), dot);
    dot = fmaf(bfhi(q.w), bfhi(k.w), dot);
  }
  escore[p] = __expf(dot * 0.15811388300841897f);
}

// ---------------- transformer aggregation + log_softmax (8 edges/half) ---------
__global__ __launch_bounds__(256) void k_agg2(
    const int* __restrict__ srcidx, const int* __restrict__ offs,
    const int* __restrict__ cnt, const ushort_t* __restrict__ QKVSb,
    const float* __restrict__ escore, float* __restrict__ out) {
  int node = (blockIdx.x * blockDim.x + threadIdx.x) >> 6;
  int lane = threadIdx.x & 63;
  if (node >= NN) return;
  const int half = lane >> 5;
  const int fl = lane & 31;   // feature-pair index (feats 2fl, 2fl+1 of 40)
  const bool valid = fl < 20;
  int beg = offs[node];
  int end = beg + cnt[node];
  float den = 0.f, av0 = 0.f, av1 = 0.f;
  const int VOFF = 64;  // v segment start in uint units (QW/2=128 uints/row)
  int p = beg + half;
  for (; p + 14 < end; p += 16) {
    int sI[8];
    float eI[8];
    uint_t vI[8];
#pragma unroll
    for (int k = 0; k < 8; ++k) {
      sI[k] = srcidx[p + 2 * k];
      eI[k] = escore[p + 2 * k];
    }
#pragma unroll
    for (int k = 0; k < 8; ++k)
      vI[k] = valid ? ((const uint_t*)QKVSb)[(size_t)sI[k] * 128 + VOFF + fl]
                    : 0u;
#pragma unroll
    for (int k = 0; k < 8; ++k) {
      av0 = fmaf(eI[k], bflo(vI[k]), av0);
      av1 = fmaf(eI[k], bfhi(vI[k]), av1);
      den += eI[k];
    }
  }
  for (; p < end; p += 2) {
    int sA = srcidx[p];
    float eA = escore[p];
    uint_t vA = valid ? ((const uint_t*)QKVSb)[(size_t)sA * 128 + VOFF + fl] : 0u;
    av0 = fmaf(eA, bflo(vA), av0); av1 = fmaf(eA, bfhi(vA), av1);
    den += eA;
  }
  // fold halves
  av0 += __shfl_xor(av0, 32, 64);
  av1 += __shfl_xor(av1, 32, 64);
  den += __shfl_xor(den, 32, 64);
  uint_t sk = valid ? ((const uint_t*)QKVSb)[(size_t)node * 128 + 96 + fl] : 0u;
  float di = 1.0f / (den + 1e-16f);
  float o0 = valid ? av0 * di + bflo(sk) : -3.0e38f;
  float o1 = valid ? av1 * di + bfhi(sk) : -3.0e38f;
  float m = half_max(fmaxf(o0, o1));
  float eo = valid ? __expf(o0 - m) + __expf(o1 - m) : 0.f;
  float ls = logf(half_sum(eo));
  if (valid && half == 0) {
    float2 r = make_float2(o0 - m - ls, o1 - m - ls);
    ((float2*)out)[(size_t)node * 20 + fl] = r;
  }
}

extern "C" void kernel_launch(void* const* d_in, const int* in_sizes, int n_in,
                              void* d_out, int out_size, void* d_ws,
                              size_t ws_size, hipStream_t stream) {
  const float* x     = (const float*)d_in[0];
  const int*   ei    = (const int*)d_in[1];
  const float* w     = (const float*)d_in[2];
  const float* W_gcn = (const float*)d_in[3];
  const float* b_gcn = (const float*)d_in[4];
  const float* Wl    = (const float*)d_in[5];
  const float* bl    = (const float*)d_in[6];
  const float* Wr    = (const float*)d_in[7];
  const float* W_gat = (const float*)d_in[8];
  const float* att_s = (const float*)d_in[9];
  const float* att_d = (const float*)d_in[10];
  const float* b_gat = (const float*)d_in[11];
  const float* Wq    = (const float*)d_in[12];
  const float* bq    = (const float*)d_in[13];
  const float* Wk    = (const float*)d_in[14];
  const float* bk    = (const float*)d_in[15];
  const float* Wv    = (const float*)d_in[16];
  const float* bv    = (const float*)d_in[17];
  const float* Wsk   = (const float*)d_in[18];
  const float* bsk   = (const float*)d_in[19];
  float* out = (float*)d_out;
  float* ws  = (float*)d_ws;

  const int* src = ei;
  const int* dst = ei + EE;

  // workspace layout (float-unit offsets).
  // qkvsb OVERLAYS aggu (aggu dead after k_post; qkvsb written after).
  uint_t*   xbu    = (uint_t*)ws;                         // 64N fl
  uint_t*   aggu   = (uint_t*)(ws + (size_t)64 * NN);     // 192N fl
  ushort_t* qkvsb  = (ushort_t*)(ws + (size_t)64 * NN);   // 128N fl (overlay)
  ushort_t* ensb   = (ushort_t*)(ws + (size_t)256 * NN);  // 32N fl
  float*    a_s    = ws + (size_t)288 * NN;               // N
  float*    a_d    = ws + (size_t)289 * NN;               // N
  float*    dinv   = ws + (size_t)290 * NN;               // N
  float2*   auxS   = (float2*)(ws + (size_t)291 * NN);    // 2N
  float2*   auxD   = (float2*)(ws + (size_t)293 * NN);    // 2N
  ushort_t* xb8    = (ushort_t*)(ws + (size_t)295 * NN);  // 32N fl (64N ush)
  float*    wv     = ws + (size_t)327 * NN;               // 256 fl
  ushort_t* WtA    = (ushort_t*)(ws + (size_t)327 * NN + 256);    // 16384 fl
  ushort_t* WtB    = (ushort_t*)(ws + (size_t)327 * NN + 16640);  // 5120 fl
  float*    bcat   = ws + (size_t)327 * NN + 21760;       // 160 fl
  float*    escore = ws + (size_t)327 * NN + 21920;       // EE fl
  float2*   edata  = (float2*)(ws + (size_t)327 * NN + 21920 + EE);  // 2EE fl
  int*      ibase  = (int*)(ws + (size_t)327 * NN + 21920 + 3 * (size_t)EE);
  int*      cnt    = ibase;                               // N
  int*      offs   = ibase + NN;                          // N
  int*      srcidx = ibase + 2 * NN;                      // EE
  int*      dsts   = ibase + 2 * NN + EE;                 // EE
  int*      erank  = ibase + 2 * NN + 2 * EE;             // EE
  int*      esorted= ibase + 2 * NN + 3 * EE;             // EE
  int*      bsum   = ibase + 2 * NN + 4 * EE;             // 256
  uchar_t*  histG  = (uchar_t*)(ibase + 2 * NN + 4 * EE + 256);  // NHB*N uchar
  int*      baseT  = (int*)(histG + (size_t)NHB * NN);    // NHB*N ints

  k_prep<<<PREP_W + 1 + PREP_X, 256, 0, stream>>>(
      x, W_gcn, Wl, W_gat, Wr, Wq, Wk, Wv, Wsk, bq, bk, bv, bsk, att_s, att_d,
      WtA, WtB, bcat, wv, xbu, xb8, a_s, a_d);
  k_hist<<<NHB, 1024, 0, stream>>>(dst, erank, histG);
  k_bsum<<<NBLK, SCB, 0, stream>>>(histG, bsum);
  k_scanapply<<<NBLK, SCB, 0, stream>>>(histG, bsum, a_s, a_d, cnt, offs,
                                        baseT, dinv, auxS, auxD);
  k_sc1<<<(EE + 255) / 256, 256, 0, stream>>>(dst, erank, baseT, esorted);
  k_sc2<<<(EE + 255) / 256, 256, 0, stream>>>(esorted, src, dst, auxS, auxD,
                                              srcidx, dsts, edata);
  k_agg1x<<<(NN + 3) / 4, 256, 0, stream>>>(srcidx, offs, cnt, (uint_t*)xb8,
                                            xbu, edata, dinv, a_s, a_d, aggu);
  k_post<<<(NN + 63) / 64, 256, 0, stream>>>((const ushort_t*)aggu,
                                             (const ushort_t*)xbu, WtA, b_gcn,
                                             bl, b_gat, w, ensb);
  k_gemmB<<<(NN + 63) / 64, 256, 0, stream>>>(ensb, WtB, bcat, qkvsb);
  k_score<<<(EE + 255) / 256, 256, 0, stream>>>(srcidx, dsts, qkvsb, escore);
  k_agg2<<<(NN + 3) / 4, 256, 0, stream>>>(srcidx, offs, cnt, qkvsb, escore,
                                           out);
}

// Round 22
// 189.640 us; speedup vs baseline: 1.0683x; 1.0683x over previous
//
#include <hip/hip_runtime.h>
#include <math.h>

#define NN 50000
#define EE 800000
#define FIN 128
#define HID 64
#define CL 40
#define SCB 256
#define NBLK ((NN + SCB - 1) / SCB)  // 196
#define NHB 64       // histogram blocks
#define EPB 12500    // EE / NHB
#define QW 256  // QKVS row width in ushorts (512B, line-aligned segments)

typedef unsigned char uchar_t;
typedef unsigned short ushort_t;
typedef unsigned int uint_t;
typedef float f32x2 __attribute__((ext_vector_type(2)));
typedef float f32x4 __attribute__((ext_vector_type(4)));
typedef short s16x8 __attribute__((ext_vector_type(8)));

#if defined(__has_builtin)
#if __has_builtin(__builtin_amdgcn_cvt_pk_f32_fp8)
#define HAVE_CVT_FP8 1
#endif
#endif

__device__ __forceinline__ ushort_t f2bf(float f) {
  uint_t u = __float_as_uint(f);
  u = (u + 0x7FFFu + ((u >> 16) & 1u)) >> 16;  // RNE
  return (ushort_t)u;
}
__device__ __forceinline__ uint_t f2bf2(float lo, float hi) {
  return (uint_t)f2bf(lo) | ((uint_t)f2bf(hi) << 16);
}
__device__ __forceinline__ float bflo(uint_t u) {
  return __uint_as_float(u << 16);
}
__device__ __forceinline__ float bfhi(uint_t u) {
  return __uint_as_float(u & 0xFFFF0000u);
}

// e4m3fn (OCP) manual encode, RNE; |x|<2^-6 flushed to 0; clamp 448.
__device__ __forceinline__ uint_t f32_to_fp8(float f) {
  uint_t u = __float_as_uint(f);
  uint_t s = (u >> 31) << 7;
  uint_t mag = u & 0x7FFFFFFFu;
  if (mag < 0x3C800000u) return s;            // < 2^-6 -> 0
  if (mag > 0x43E00000u) mag = 0x43E00000u;   // clamp 448
  uint_t r = mag + 0x7FFFFu + ((mag >> 20) & 1u);
  if (r > 0x43E00000u) r = 0x43E00000u;
  return s | (((r - (120u << 23)) >> 20) & 0x7Fu);
}
__device__ __forceinline__ void fp8x4_to_f32(uint_t u, float* o) {
#ifdef HAVE_CVT_FP8
  f32x2 lo = __builtin_amdgcn_cvt_pk_f32_fp8(u, false);
  f32x2 hi = __builtin_amdgcn_cvt_pk_f32_fp8(u, true);
  o[0] = lo[0]; o[1] = lo[1]; o[2] = hi[0]; o[3] = hi[1];
#else
#pragma unroll
  for (int i = 0; i < 4; ++i) {
    uint_t b = (u >> (8 * i)) & 0xFFu;
    uint_t em = b & 0x7Fu;
    uint_t bits = ((b & 0x80u) << 24) | ((em << 20) + (120u << 23));
    o[i] = em ? __uint_as_float(bits) : 0.f;
  }
#endif
}

__device__ __forceinline__ int wave_sum_i(int v) {
#pragma unroll
  for (int off = 32; off > 0; off >>= 1) v += __shfl_xor(v, off, 64);
  return v;
}
__device__ __forceinline__ float wave_sum_f(float v) {
#pragma unroll
  for (int off = 32; off > 0; off >>= 1) v += __shfl_xor(v, off, 64);
  return v;
}
__device__ __forceinline__ float half_sum(float v) {  // within 32-lane half
#pragma unroll
  for (int off = 16; off > 0; off >>= 1) v += __shfl_xor(v, off, 64);
  return v;
}
__device__ __forceinline__ float half_max(float v) {
#pragma unroll
  for (int off = 16; off > 0; off >>= 1) v = fmaxf(v, __shfl_xor(v, off, 64));
  return v;
}
__device__ __forceinline__ float gelu_exact(float x) {
  return 0.5f * x * (1.0f + erff(x * 0.70710678118654752f));
}
__device__ __forceinline__ float leaky02(float x) {
  return x >= 0.f ? x : 0.2f * x;
}

// ------------- fused prep: prepw | wvec | xcast(+fp8) --------------------------
#define PREP_W 169       // ceil(43168/256)
#define PREP_X 12500     // NN/4 nodes per 256-thread block
__global__ __launch_bounds__(256) void k_prep(
    const float* __restrict__ x,
    const float* __restrict__ W0, const float* __restrict__ W1,
    const float* __restrict__ W2, const float* __restrict__ W3,
    const float* __restrict__ Q0, const float* __restrict__ Q1,
    const float* __restrict__ Q2, const float* __restrict__ Q3,
    const float* __restrict__ b0, const float* __restrict__ b1,
    const float* __restrict__ b2, const float* __restrict__ b3,
    const float* __restrict__ attS, const float* __restrict__ attD,
    ushort_t* __restrict__ WtA, ushort_t* __restrict__ WtB,
    float* __restrict__ bcat, float* __restrict__ wv,
    uint_t* __restrict__ xbu, ushort_t* __restrict__ xb8,
    float* __restrict__ a_s, float* __restrict__ a_d) {
  int b = blockIdx.x, t = threadIdx.x;
  if (b < PREP_W) {
    int idx = b * 256 + t;
    if (idx < 32768) {
      int m = idx >> 13, r = idx & 8191, c = r >> 7, k = r & 127;
      const float* W = (m == 0) ? W0 : (m == 1) ? W1 : (m == 2) ? W2 : W3;
      WtA[idx] = f2bf(W[k * HID + c]);
    } else if (idx < 43008) {
      int j = idx - 32768;
      int c = j >> 6, k = j & 63;
      int mm = c / CL, cc = c % CL;
      const float* W = (mm == 0) ? Q0 : (mm == 1) ? Q1 : (mm == 2) ? Q2 : Q3;
      WtB[j] = f2bf(W[k * CL + cc]);
    } else if (idx < 43168) {
      int c = idx - 43008;
      int mm = c / CL, cc = c % CL;
      const float* bb = (mm == 0) ? b0 : (mm == 1) ? b1 : (mm == 2) ? b2 : b3;
      bcat[c] = bb[cc];
    }
  } else if (b < PREP_W + 1) {
    // wvec: wv[0][k] = sum_c W_gat[k][c]*attS[c]; wv[1][k] = ..attD
    int which = t >> 7, k = t & 127;
    const float* att = which ? attD : attS;
    float s = 0.f;
    for (int c = 0; c < HID; ++c) s = fmaf(W2[k * HID + c], att[c], s);
    wv[which * FIN + k] = s;
  } else {
    int node = (b - PREP_W - 1) * 4 + (t >> 6);
    int l = t & 63;
    if (node < NN) {
      float2 xv = ((const float2*)x)[(size_t)node * 64 + l];  // feats 2l,2l+1
      float2 wsv = ((const float2*)wv)[l];
      float2 wdv = ((const float2*)(wv + FIN))[l];
      float ps = fmaf(xv.x, wsv.x, xv.y * wsv.y);
      float pd = fmaf(xv.x, wdv.x, xv.y * wdv.y);
      ps = wave_sum_f(ps);
      pd = wave_sum_f(pd);
      xbu[(size_t)node * 64 + l] = f2bf2(xv.x, xv.y);
      xb8[(size_t)node * 64 + l] =
          (ushort_t)(f32_to_fp8(xv.x) | (f32_to_fp8(xv.y) << 8));
      if (l == 0) { a_s[node] = ps; a_d[node] = pd; }
    }
  }
}

// ------------- LDS histogram, single pass, 8-bit packed counters ---------------
__global__ __launch_bounds__(1024) void k_hist(const int* __restrict__ dst,
                                               int* __restrict__ erank,
                                               uchar_t* __restrict__ histG) {
  __shared__ uint_t hl[NN / 4];  // 12500 uints = 50000 byte counters
  int b = blockIdx.x, t = threadIdx.x;
  for (int i = t; i < NN / 4; i += 1024) hl[i] = 0;
  __syncthreads();
  int ebase = b * EPB;
  for (int i = t; i < EPB; i += 1024) {
    int e = ebase + i;
    int d = dst[e];
    uint_t sh = (uint_t)(d & 3) * 8u;
    uint_t old = atomicAdd(&hl[d >> 2], 1u << sh);
    erank[e] = (int)((old >> sh) & 0xFFu);
  }
  __syncthreads();
  uint_t* hg = (uint_t*)(histG + (size_t)b * NN);
  for (int i = t; i < NN / 4; i += 1024) hg[i] = hl[i];
}

// ---------------- block sums over the 64 mini-histograms -----------------------
__global__ __launch_bounds__(SCB) void k_bsum(const uchar_t* __restrict__ histG,
                                              int* __restrict__ bsum) {
  __shared__ int wsm[4];
  int i = blockIdx.x * SCB + threadIdx.x;
  int v = 0;
  if (i < NN) {
    for (int r = 0; r < NHB; ++r) v += histG[(size_t)r * NN + i];
  }
  int s = wave_sum_i(v);
  int lane = threadIdx.x & 63, wv = threadIdx.x >> 6;
  if (lane == 0) wsm[wv] = s;
  __syncthreads();
  if (threadIdx.x == 0) bsum[blockIdx.x] = wsm[0] + wsm[1] + wsm[2] + wsm[3];
}

// ---------------- fused bscan+apply + per-histblock bases + aux packs ----------
__global__ __launch_bounds__(SCB) void k_scanapply(
    const uchar_t* __restrict__ histG, const int* __restrict__ bsum,
    const float* __restrict__ a_s, const float* __restrict__ a_d,
    int* __restrict__ cnt, int* __restrict__ offs, int* __restrict__ baseT,
    float* __restrict__ dinv, float2* __restrict__ auxS,
    float2* __restrict__ auxD) {
  __shared__ int ts[SCB];
  __shared__ int wred[4];
  int b = blockIdx.x, t = threadIdx.x;
  int pv = (t < b) ? bsum[t] : 0;  // b<=195, t<b implies t<196=NBLK
  int ps = wave_sum_i(pv);
  int lane = t & 63, wv = t >> 6;
  if (lane == 0) wred[wv] = ps;
  int i = b * SCB + t;
  int v = 0;
  if (i < NN) {
    for (int r = 0; r < NHB; ++r) v += histG[(size_t)r * NN + i];
  }
  ts[t] = v;
  __syncthreads();
  int prefix = wred[0] + wred[1] + wred[2] + wred[3];
  for (int off = 1; off < SCB; off <<= 1) {
    int u = (t >= off) ? ts[t - off] : 0;
    __syncthreads();
    ts[t] += u;
    __syncthreads();
  }
  if (i < NN) {
    int ex = ts[t] - v + prefix;
    offs[i] = ex;
    cnt[i] = v;
    float dv = rsqrtf((float)v + 1.0f);
    dinv[i] = dv;
    auxS[i] = make_float2(dv, a_s[i]);
    auxD[i] = make_float2(dv, a_d[i]);
    int run = ex;
    for (int r = 0; r < NHB; ++r) {
      baseT[(size_t)r * NN + i] = run;
      run += histG[(size_t)r * NN + i];
    }
  }
}

// ---------------- scatter pass 1: inverse permutation only (4B/edge) -----------
__global__ __launch_bounds__(256) void k_sc1(const int* __restrict__ dst,
                                             const int* __restrict__ erank,
                                             const int* __restrict__ baseT,
                                             int* __restrict__ esorted) {
  int e = blockIdx.x * blockDim.x + threadIdx.x;
  if (e < EE) {
    int d = dst[e];
    int blk = e / EPB;  // must match k_hist's block->edge mapping
    esorted[baseT[(size_t)blk * NN + d] + erank[e]] = e;
  }
}

// ---------------- scatter pass 2: p-coalesced fill of sorted arrays ------------
__global__ __launch_bounds__(256) void k_sc2(
    const int* __restrict__ esorted, const int* __restrict__ src,
    const int* __restrict__ dst, const float2* __restrict__ auxS,
    const float2* __restrict__ auxD, int* __restrict__ srcidx,
    int* __restrict__ dsts, float2* __restrict__ edata) {
  int p = blockIdx.x * blockDim.x + threadIdx.x;
  if (p < EE) {
    int e = esorted[p];
    int s = src[e], d = dst[e];
    srcidx[p] = s;
    dsts[p] = d;
    float2 A = auxS[s];  // {dinv_s, a_s_s}
    float2 B = auxD[d];  // {dinv_d, a_d_d}
    float ex = __expf(leaky02(A.y + B.y));
    edata[p] = make_float2(A.x * B.x, ex);
  }
}

// ---------------- x-space aggregation (fp8 gathers, 4 edges/half in flight) ----
__global__ __launch_bounds__(256) void k_agg1x(
    const int* __restrict__ srcidx, const int* __restrict__ offs,
    const int* __restrict__ cnt, const uint_t* __restrict__ xb8u,
    const uint_t* __restrict__ xbu, const float2* __restrict__ edata,
    const float* __restrict__ dinv, const float* __restrict__ a_s,
    const float* __restrict__ a_d, uint_t* __restrict__ aggu) {
  int node = (blockIdx.x * blockDim.x + threadIdx.x) >> 6;
  int lane = threadIdx.x & 63;
  if (node >= NN) return;
  const int half = lane >> 5;
  const int fl = lane & 31;
  int beg = offs[node];
  int c = cnt[node];
  int end = beg + c;
  float g[4] = {0.f, 0.f, 0.f, 0.f};
  float sS[4] = {0.f, 0.f, 0.f, 0.f};
  float tA[4] = {0.f, 0.f, 0.f, 0.f};
  float dg = 0.f;
  int p = beg + half;
  for (; p + 6 < end; p += 8) {
    int s0 = srcidx[p], s1 = srcidx[p + 2], s2 = srcidx[p + 4],
        s3 = srcidx[p + 6];
    float2 e0 = edata[p], e1 = edata[p + 2], e2 = edata[p + 4],
           e3 = edata[p + 6];
    uint_t u0 = xb8u[(size_t)s0 * 32 + fl];
    uint_t u1 = xb8u[(size_t)s1 * 32 + fl];
    uint_t u2 = xb8u[(size_t)s2 * 32 + fl];
    uint_t u3 = xb8u[(size_t)s3 * 32 + fl];
    float A[4], B[4], C[4], D[4];
    fp8x4_to_f32(u0, A);
    fp8x4_to_f32(u1, B);
    fp8x4_to_f32(u2, C);
    fp8x4_to_f32(u3, D);
#pragma unroll
    for (int i = 0; i < 4; ++i) {
      g[i] = fmaf(A[i], e0.x, g[i]);
      g[i] = fmaf(B[i], e1.x, g[i]);
      g[i] = fmaf(C[i], e2.x, g[i]);
      g[i] = fmaf(D[i], e3.x, g[i]);
      sS[i] += (A[i] + B[i]) + (C[i] + D[i]);
      tA[i] = fmaf(A[i], e0.y, tA[i]);
      tA[i] = fmaf(B[i], e1.y, tA[i]);
      tA[i] = fmaf(C[i], e2.y, tA[i]);
      tA[i] = fmaf(D[i], e3.y, tA[i]);
    }
    dg += (e0.y + e1.y) + (e2.y + e3.y);
  }
  for (; p < end; p += 2) {
    int s0 = srcidx[p];
    float2 e0 = edata[p];
    uint_t u0 = xb8u[(size_t)s0 * 32 + fl];
    float A[4];
    fp8x4_to_f32(u0, A);
#pragma unroll
    for (int i = 0; i < 4; ++i) {
      g[i] = fmaf(A[i], e0.x, g[i]);
      sS[i] += A[i];
      tA[i] = fmaf(A[i], e0.y, tA[i]);
    }
    dg += e0.y;
  }
  // fold halves
#pragma unroll
  for (int i = 0; i < 4; ++i) {
    g[i] += __shfl_xor(g[i], 32, 64);
    sS[i] += __shfl_xor(sS[i], 32, 64);
    tA[i] += __shfl_xor(tA[i], 32, 64);
  }
  dg += __shfl_xor(dg, 32, 64);
  // self-loops (bf16 x) + scaling
  float dd = dinv[node];
  float exl = __expf(leaky02(a_s[node] + a_d[node]));
  uint_t n0 = xbu[(size_t)node * 64 + 2 * fl];
  uint_t n1 = xbu[(size_t)node * 64 + 2 * fl + 1];
  float X[4] = {bflo(n0), bfhi(n0), bflo(n1), bfhi(n1)};
  float dd2 = dd * dd;
  float cinv = 1.0f / fmaxf((float)c, 1.0f);
  float gdi = 1.0f / (dg + exl + 1e-16f);
#pragma unroll
  for (int i = 0; i < 4; ++i) {
    g[i] = fmaf(X[i], dd2, g[i]);
    tA[i] = fmaf(X[i], exl, tA[i]);
    sS[i] *= cinv;
    tA[i] *= gdi;
  }
  if (half == 0) {
    uint_t* ag = aggu + (size_t)node * 192;
    ag[2 * fl] = f2bf2(g[0], g[1]);
    ag[2 * fl + 1] = f2bf2(g[2], g[3]);
    ag[64 + 2 * fl] = f2bf2(sS[0], sS[1]);
    ag[64 + 2 * fl + 1] = f2bf2(sS[2], sS[3]);
    ag[128 + 2 * fl] = f2bf2(tA[0], tA[1]);
    ag[128 + 2 * fl + 1] = f2bf2(tA[2], tA[3]);
  }
}

// ---------------- post GEMM: 4 MFMA matmuls + gelu ensemble --------------------
__global__ __launch_bounds__(256) void k_post(
    const ushort_t* __restrict__ agg, const ushort_t* __restrict__ xb,
    const ushort_t* __restrict__ WtA, const float* __restrict__ b_gcn,
    const float* __restrict__ bl, const float* __restrict__ b_gat,
    const float* __restrict__ w, ushort_t* __restrict__ ensb) {
  __shared__ __align__(16) ushort_t wlds[64 * 136];  // [c][k] pad +8
  const int t = threadIdx.x;
  const int wv = t >> 6, l = t & 63;
  const int lr = l & 15, lg = l >> 4;
  const int rbase = blockIdx.x * 64 + wv * 16;
  int arow = rbase + lr;
  int arowc = arow < NN ? arow : NN - 1;
  f32x4 acc[4][4] = {};
#pragma unroll
  for (int m = 0; m < 4; ++m) {
    if (m) __syncthreads();
    for (int idx = t; idx < 64 * 16; idx += 256) {
      int c = idx >> 4, ch = idx & 15;
      *(uint4*)&wlds[c * 136 + ch * 8] =
          *(const uint4*)(WtA + m * 8192 + c * 128 + ch * 8);
    }
    __syncthreads();
    const ushort_t* ap = (m < 3) ? agg + (size_t)arowc * 384 + m * 128 + lg * 8
                                 : xb + (size_t)arowc * 128 + lg * 8;
#pragma unroll
    for (int ks = 0; ks < 4; ++ks) {
      s16x8 af = *(const s16x8*)(ap + ks * 32);
#pragma unroll
      for (int n = 0; n < 4; ++n) {
        s16x8 bf = *(const s16x8*)&wlds[(n * 16 + lr) * 136 + ks * 32 + lg * 8];
        acc[m][n] =
            __builtin_amdgcn_mfma_f32_16x16x32_bf16(af, bf, acc[m][n], 0, 0, 0);
      }
    }
  }
  float w0 = w[0], w1 = w[1], w2 = w[2];
#pragma unroll
  for (int n = 0; n < 4; ++n) {
    int col = n * 16 + lr;
    float bgv = b_gcn[col], bsv = bl[col], bav = b_gat[col];
#pragma unroll
    for (int j = 0; j < 4; ++j) {
      int orow = rbase + lg * 4 + j;
      if (orow < NN) {
        float g = gelu_exact(acc[0][n][j] + bgv);
        float s = gelu_exact(acc[1][n][j] + acc[3][n][j] + bsv);
        float tt = gelu_exact(acc[2][n][j] + bav);
        ensb[(size_t)orow * 64 + col] = f2bf(w0 * g + w1 * s + w2 * tt);
      }
    }
  }
}

// ---------------- MFMA GEMM B: line-aligned QKVS (segments at 0/64/128/192) ----
__global__ __launch_bounds__(256) void k_gemmB(
    const ushort_t* __restrict__ ensb, const ushort_t* __restrict__ WtB,
    const float* __restrict__ bcat, ushort_t* __restrict__ QKVSb) {
  __shared__ __align__(16) ushort_t wb[160 * 72];  // [c][k] padded +8
  __shared__ float bsh[160];
  const int t = threadIdx.x;
  for (int idx = t; idx < 160 * 8; idx += 256) {
    int c = idx >> 3, ch = idx & 7;
    *(uint4*)&wb[c * 72 + ch * 8] = *(const uint4*)(WtB + c * 64 + ch * 8);
  }
  if (t < 160) bsh[t] = bcat[t];
  __syncthreads();
  const int wv = t >> 6, l = t & 63;
  const int lr = l & 15, lg = l >> 4;
  const int rbase = blockIdx.x * 64 + wv * 16;
  int arow = rbase + lr;
  int arowc = arow < NN ? arow : NN - 1;
  const ushort_t* ap = ensb + (size_t)arowc * 64 + lg * 8;
  f32x4 acc[10] = {};
#pragma unroll
  for (int ks = 0; ks < 2; ++ks) {
    s16x8 af = *(const s16x8*)(ap + ks * 32);
#pragma unroll
    for (int n = 0; n < 10; ++n) {
      s16x8 bf = *(const s16x8*)&wb[(n * 16 + lr) * 72 + ks * 32 + lg * 8];
      acc[n] = __builtin_amdgcn_mfma_f32_16x16x32_bf16(af, bf, acc[n], 0, 0, 0);
    }
  }
#pragma unroll
  for (int n = 0; n < 10; ++n) {
    int col = n * 16 + lr;
    int seg = col / CL;
    int off = seg * 64 + (col - seg * CL);
#pragma unroll
    for (int j = 0; j < 4; ++j) {
      int orow = rbase + lg * 4 + j;
      if (orow < NN)
        QKVSb[(size_t)orow * QW + off] = f2bf(acc[n][j] + bsh[col]);
    }
  }
}

// ---------------- transformer scores: lane per edge (no shuffles) --------------
__global__ __launch_bounds__(256) void k_score(
    const int* __restrict__ srcidx, const int* __restrict__ dsts,
    const ushort_t* __restrict__ QKVSb, float* __restrict__ escore) {
  int p = blockIdx.x * 256 + threadIdx.x;
  if (p >= EE) return;
  int s = srcidx[p], d = dsts[p];
  const uint4* qp = (const uint4*)(QKVSb + (size_t)d * QW);       // q: line 0
  const uint4* kp = (const uint4*)(QKVSb + (size_t)s * QW + 64);  // k: line 1
  float dot = 0.f;
#pragma unroll
  for (int i = 0; i < 5; ++i) {
    uint4 q = qp[i], k = kp[i];
    dot = fmaf(bflo(q.x), bflo(k.x), dot);
    dot = fmaf(bfhi(q.x), bfhi(k.x), dot);
    dot = fmaf(bflo(q.y), bflo(k.y), dot);
    dot = fmaf(bfhi(q.y), bfhi(k.y), dot);
    dot = fmaf(bflo(q.z), bflo(k.z), dot);
    dot = fmaf(bfhi(q.z), bfhi(k.z), dot);
    dot = fmaf(bflo(q.w), bflo(k.w), dot);
    dot = fmaf(bfhi(q.w), bfhi(k.w), dot);
  }
  escore[p] = __expf(dot * 0.15811388300841897f);
}

// ---------------- transformer aggregation + log_softmax (4 edges/half) ---------
__global__ __launch_bounds__(256) void k_agg2(
    const int* __restrict__ srcidx, const int* __restrict__ offs,
    const int* __restrict__ cnt, const ushort_t* __restrict__ QKVSb,
    const float* __restrict__ escore, float* __restrict__ out) {
  int node = (blockIdx.x * blockDim.x + threadIdx.x) >> 6;
  int lane = threadIdx.x & 63;
  if (node >= NN) return;
  const int half = lane >> 5;
  const int fl = lane & 31;   // feature-pair index (feats 2fl, 2fl+1 of 40)
  const bool valid = fl < 20;
  int beg = offs[node];
  int end = beg + cnt[node];
  float den = 0.f, av0 = 0.f, av1 = 0.f;
  const int VOFF = 64;  // v segment start in uint units (QW/2=128 uints/row)
  int p = beg + half;
  for (; p + 6 < end; p += 8) {
    int sA = srcidx[p], sB = srcidx[p + 2], sC = srcidx[p + 4],
        sD = srcidx[p + 6];
    float eA = escore[p], eB = escore[p + 2], eC = escore[p + 4],
          eD = escore[p + 6];
    uint_t vA = valid ? ((const uint_t*)QKVSb)[(size_t)sA * 128 + VOFF + fl] : 0u;
    uint_t vB = valid ? ((const uint_t*)QKVSb)[(size_t)sB * 128 + VOFF + fl] : 0u;
    uint_t vC = valid ? ((const uint_t*)QKVSb)[(size_t)sC * 128 + VOFF + fl] : 0u;
    uint_t vD = valid ? ((const uint_t*)QKVSb)[(size_t)sD * 128 + VOFF + fl] : 0u;
    av0 = fmaf(eA, bflo(vA), av0); av1 = fmaf(eA, bfhi(vA), av1);
    av0 = fmaf(eB, bflo(vB), av0); av1 = fmaf(eB, bfhi(vB), av1);
    av0 = fmaf(eC, bflo(vC), av0); av1 = fmaf(eC, bfhi(vC), av1);
    av0 = fmaf(eD, bflo(vD), av0); av1 = fmaf(eD, bfhi(vD), av1);
    den += (eA + eB) + (eC + eD);
  }
  for (; p < end; p += 2) {
    int sA = srcidx[p];
    float eA = escore[p];
    uint_t vA = valid ? ((const uint_t*)QKVSb)[(size_t)sA * 128 + VOFF + fl] : 0u;
    av0 = fmaf(eA, bflo(vA), av0); av1 = fmaf(eA, bfhi(vA), av1);
    den += eA;
  }
  // fold halves
  av0 += __shfl_xor(av0, 32, 64);
  av1 += __shfl_xor(av1, 32, 64);
  den += __shfl_xor(den, 32, 64);
  uint_t sk = valid ? ((const uint_t*)QKVSb)[(size_t)node * 128 + 96 + fl] : 0u;
  float di = 1.0f / (den + 1e-16f);
  float o0 = valid ? av0 * di + bflo(sk) : -3.0e38f;
  float o1 = valid ? av1 * di + bfhi(sk) : -3.0e38f;
  float m = half_max(fmaxf(o0, o1));
  float eo = valid ? __expf(o0 - m) + __expf(o1 - m) : 0.f;
  float ls = logf(half_sum(eo));
  if (valid && half == 0) {
    float2 r = make_float2(o0 - m - ls, o1 - m - ls);
    ((float2*)out)[(size_t)node * 20 + fl] = r;
  }
}

extern "C" void kernel_launch(void* const* d_in, const int* in_sizes, int n_in,
                              void* d_out, int out_size, void* d_ws,
                              size_t ws_size, hipStream_t stream) {
  const float* x     = (const float*)d_in[0];
  const int*   ei    = (const int*)d_in[1];
  const float* w     = (const float*)d_in[2];
  const float* W_gcn = (const float*)d_in[3];
  const float* b_gcn = (const float*)d_in[4];
  const float* Wl    = (const float*)d_in[5];
  const float* bl    = (const float*)d_in[6];
  const float* Wr    = (const float*)d_in[7];
  const float* W_gat = (const float*)d_in[8];
  const float* att_s = (const float*)d_in[9];
  const float* att_d = (const float*)d_in[10];
  const float* b_gat = (const float*)d_in[11];
  const float* Wq    = (const float*)d_in[12];
  const float* bq    = (const float*)d_in[13];
  const float* Wk    = (const float*)d_in[14];
  const float* bk    = (const float*)d_in[15];
  const float* Wv    = (const float*)d_in[16];
  const float* bv    = (const float*)d_in[17];
  const float* Wsk   = (const float*)d_in[18];
  const float* bsk   = (const float*)d_in[19];
  float* out = (float*)d_out;
  float* ws  = (float*)d_ws;

  const int* src = ei;
  const int* dst = ei + EE;

  // workspace layout (float-unit offsets).
  // qkvsb OVERLAYS aggu (aggu dead after k_post; qkvsb written after).
  uint_t*   xbu    = (uint_t*)ws;                         // 64N fl
  uint_t*   aggu   = (uint_t*)(ws + (size_t)64 * NN);     // 192N fl
  ushort_t* qkvsb  = (ushort_t*)(ws + (size_t)64 * NN);   // 128N fl (overlay)
  ushort_t* ensb   = (ushort_t*)(ws + (size_t)256 * NN);  // 32N fl
  float*    a_s    = ws + (size_t)288 * NN;               // N
  float*    a_d    = ws + (size_t)289 * NN;               // N
  float*    dinv   = ws + (size_t)290 * NN;               // N
  float2*   auxS   = (float2*)(ws + (size_t)291 * NN);    // 2N
  float2*   auxD   = (float2*)(ws + (size_t)293 * NN);    // 2N
  ushort_t* xb8    = (ushort_t*)(ws + (size_t)295 * NN);  // 32N fl (64N ush)
  float*    wv     = ws + (size_t)327 * NN;               // 256 fl
  ushort_t* WtA    = (ushort_t*)(ws + (size_t)327 * NN + 256);    // 16384 fl
  ushort_t* WtB    = (ushort_t*)(ws + (size_t)327 * NN + 16640);  // 5120 fl
  float*    bcat   = ws + (size_t)327 * NN + 21760;       // 160 fl
  float*    escore = ws + (size_t)327 * NN + 21920;       // EE fl
  float2*   edata  = (float2*)(ws + (size_t)327 * NN + 21920 + EE);  // 2EE fl
  int*      ibase  = (int*)(ws + (size_t)327 * NN + 21920 + 3 * (size_t)EE);
  int*      cnt    = ibase;                               // N
  int*      offs   = ibase + NN;                          // N
  int*      srcidx = ibase + 2 * NN;                      // EE
  int*      dsts   = ibase + 2 * NN + EE;                 // EE
  int*      erank  = ibase + 2 * NN + 2 * EE;             // EE
  int*      esorted= ibase + 2 * NN + 3 * EE;             // EE
  int*      bsum   = ibase + 2 * NN + 4 * EE;             // 256
  uchar_t*  histG  = (uchar_t*)(ibase + 2 * NN + 4 * EE + 256);  // NHB*N uchar
  int*      baseT  = (int*)(histG + (size_t)NHB * NN);    // NHB*N ints

  k_prep<<<PREP_W + 1 + PREP_X, 256, 0, stream>>>(
      x, W_gcn, Wl, W_gat, Wr, Wq, Wk, Wv, Wsk, bq, bk, bv, bsk, att_s, att_d,
      WtA, WtB, bcat, wv, xbu, xb8, a_s, a_d);
  k_hist<<<NHB, 1024, 0, stream>>>(dst, erank, histG);
  k_bsum<<<NBLK, SCB, 0, stream>>>(histG, bsum);
  k_scanapply<<<NBLK, SCB, 0, stream>>>(histG, bsum, a_s, a_d, cnt, offs,
                                        baseT, dinv, auxS, auxD);
  k_sc1<<<(EE + 255) / 256, 256, 0, stream>>>(dst, erank, baseT, esorted);
  k_sc2<<<(EE + 255) / 256, 256, 0, stream>>>(esorted, src, dst, auxS, auxD,
                                              srcidx, dsts, edata);
  k_agg1x<<<(NN + 3) / 4, 256, 0, stream>>>(srcidx, offs, cnt, (uint_t*)xb8,
                                            xbu, edata, dinv, a_s, a_d, aggu);
  k_post<<<(NN + 63) / 64, 256, 0, stream>>>((const ushort_t*)aggu,
                                             (const ushort_t*)xbu, WtA, b_gcn,
                                             bl, b_gat, w, ensb);
  k_gemmB<<<(NN + 63) / 64, 256, 0, stream>>>(ensb, WtB, bcat, qkvsb);
  k_score<<<(EE + 255) / 256, 256, 0, stream>>>(srcidx, dsts, qkvsb, escore);
  k_agg2<<<(NN + 3) / 4, 256, 0, stream>>>(srcidx, offs, cnt, qkvsb, escore,
                                           out);
}